// Round 1
// baseline (202.314 us; speedup 1.0000x reference)
//
#include <hip/hip_runtime.h>

// DBSCAN neighbor-count + classify, MI355X (gfx950)
// B=4 batches, N=8192 points, D=16 features, fp32 in, int32 out.
// cond: dist(i,j) < 0.5  <=>  d2 < 0.25  <=>  dot(i,j) > g_i + g_j,
//       g_p = 0.5*||x_p||^2 - 0.125
// out[p] = (count_p < 10) ? -1 : 0

constexpr int Np = 8192;
constexpr int Bb = 4;
constexpr int Dd = 16;
constexpr int TJ = 128;            // j-points staged in LDS per tile
constexpr int JS = 8;              // j-splits (partial counts via atomicAdd)
constexpr int JCHUNK = Np / JS;    // 1024 j per block
constexpr int MIN_PTS = 10;

__global__ __launch_bounds__(256)
void dbscan_count(const float* __restrict__ x, int* __restrict__ cnt) {
    const int blk = blockIdx.x;          // 4 * 16 * 8 = 512 blocks
    const int b   = blk >> 7;            // batch
    const int it  = (blk >> 3) & 15;     // i-tile (512 i's each)
    const int js  = blk & 7;             // j-split
    const int t   = threadIdx.x;

    const float* __restrict__ xb = x + (size_t)b * Np * Dd;

    const int i0 = it * 512 + t;         // this thread's two i-rows
    const int i1 = i0 + 256;

    // Load own i-features into registers (4x float4 each)
    float xi0[Dd], xi1[Dd];
    {
        const float4* p0 = (const float4*)(xb + (size_t)i0 * Dd);
        const float4* p1 = (const float4*)(xb + (size_t)i1 * Dd);
#pragma unroll
        for (int q = 0; q < 4; q++) {
            float4 a = p0[q];
            xi0[4*q+0] = a.x; xi0[4*q+1] = a.y; xi0[4*q+2] = a.z; xi0[4*q+3] = a.w;
            float4 c = p1[q];
            xi1[4*q+0] = c.x; xi1[4*q+1] = c.y; xi1[4*q+2] = c.z; xi1[4*q+3] = c.w;
        }
    }
    float g0 = 0.f, g1 = 0.f;
#pragma unroll
    for (int k = 0; k < Dd; k++) { g0 = fmaf(xi0[k], xi0[k], g0); g1 = fmaf(xi1[k], xi1[k], g1); }
    g0 = 0.5f * g0 - 0.125f;
    g1 = 0.5f * g1 - 0.125f;

    __shared__ float xj[TJ * Dd];   // 8 KB j-tile
    __shared__ float gj[TJ];        // thresholds for tile

    int c0 = 0, c1 = 0;
    const int jbase = js * JCHUNK;

    for (int j0 = 0; j0 < JCHUNK; j0 += TJ) {
        __syncthreads();  // protect previous tile reads before overwrite
        // Stage TJ*Dd = 2048 floats = 512 float4; 2 per thread, coalesced.
        {
            const float4* src = (const float4*)(xb + (size_t)(jbase + j0) * Dd);
            float4* dst = (float4*)xj;
            dst[t]       = src[t];
            dst[t + 256] = src[t + 256];
        }
        __syncthreads();
        // Compute g_j for the tile: 4 lanes per point, shuffle-reduce.
        // float4 read at word offset 4*t -> conflict-free.
#pragma unroll
        for (int r = 0; r < 2; r++) {
            const int j = r * 64 + (t >> 2);
            const int q = t & 3;
            float4 v = ((const float4*)xj)[j * 4 + q];
            float s = v.x*v.x + v.y*v.y + v.z*v.z + v.w*v.w;
            s += __shfl_xor(s, 1);
            s += __shfl_xor(s, 2);
            if (q == 0) gj[j] = 0.5f * s - 0.125f;
        }
        __syncthreads();

        // Inner sweep: all lanes read same LDS address -> broadcast (no conflict).
#pragma unroll 2
        for (int jj = 0; jj < TJ; jj++) {
            const float4* vp = (const float4*)(xj + jj * Dd);
            float4 v0 = vp[0], v1 = vp[1], v2 = vp[2], v3 = vp[3];
            float vv[Dd];
            vv[0]=v0.x; vv[1]=v0.y; vv[2]=v0.z; vv[3]=v0.w;
            vv[4]=v1.x; vv[5]=v1.y; vv[6]=v1.z; vv[7]=v1.w;
            vv[8]=v2.x; vv[9]=v2.y; vv[10]=v2.z; vv[11]=v2.w;
            vv[12]=v3.x; vv[13]=v3.y; vv[14]=v3.z; vv[15]=v3.w;
            // two partial chains per dot for ILP (8 independent fma chains total)
            float d0a = 0.f, d0b = 0.f, d1a = 0.f, d1b = 0.f;
#pragma unroll
            for (int k = 0; k < 8; k++) {
                d0a = fmaf(xi0[k],     vv[k],     d0a);
                d0b = fmaf(xi0[k + 8], vv[k + 8], d0b);
                d1a = fmaf(xi1[k],     vv[k],     d1a);
                d1b = fmaf(xi1[k + 8], vv[k + 8], d1b);
            }
            const float g = gj[jj];
            c0 += ((d0a + d0b) > (g0 + g)) ? 1 : 0;
            c1 += ((d1a + d1b) > (g1 + g)) ? 1 : 0;
        }
    }

    atomicAdd(&cnt[b * Np + i0], c0);
    atomicAdd(&cnt[b * Np + i1], c1);
}

__global__ __launch_bounds__(256)
void dbscan_classify(int* __restrict__ cnt) {
    const int idx = blockIdx.x * 256 + threadIdx.x;
    cnt[idx] = (cnt[idx] < MIN_PTS) ? -1 : 0;
}

extern "C" void kernel_launch(void* const* d_in, const int* in_sizes, int n_in,
                              void* d_out, int out_size, void* d_ws, size_t ws_size,
                              hipStream_t stream) {
    const float* x = (const float*)d_in[0];
    int* out = (int*)d_out;   // reused as the count buffer, then classified in place

    hipMemsetAsync(out, 0, (size_t)Bb * Np * sizeof(int), stream);
    dbscan_count<<<dim3(Bb * (Np / 512) * JS), dim3(256), 0, stream>>>(x, out);
    dbscan_classify<<<dim3(Bb * Np / 256), dim3(256), 0, stream>>>(out);
}

// Round 2
// 159.876 us; speedup vs baseline: 1.2654x; 1.2654x over previous
//
#include <hip/hip_runtime.h>

// DBSCAN neighbor-count + classify via bf16 MFMA Gram matrix, MI355X (gfx950)
// B=4, N=8192, D=16 fp32 in, int32 out.
// dist(i,j) < 0.5  <=>  dot(i,j) > g_i + g_j,  g_p = 0.5*||x_p||^2 - 0.125
// S = X X^T computed with mfma_f32_32x32x16_bf16 (K=16 == D, no padding).
// acc is initialized to -(g_i + g_j) so MFMA output is S - threshold directly.
// out[p] = (count_p < 10) ? -1 : 0

constexpr int Np = 8192;
constexpr int Bb = 4;
constexpr int Dd = 16;
constexpr int MIN_PTS = 10;

typedef __bf16 bf16x8 __attribute__((ext_vector_type(8)));
typedef float f32x16 __attribute__((ext_vector_type(16)));

// ---------------- prep: fp32 -> bf16 + per-point threshold g ----------------
__global__ __launch_bounds__(256)
void dbscan_prep(const float* __restrict__ x, __bf16* __restrict__ xb,
                 float* __restrict__ g) {
    const int p = blockIdx.x * 256 + threadIdx.x;   // 32768 points
    const float4* src = (const float4*)(x + (size_t)p * Dd);
    float4 v0 = src[0], v1 = src[1], v2 = src[2], v3 = src[3];
    float vv[Dd];
    vv[0]=v0.x; vv[1]=v0.y; vv[2]=v0.z; vv[3]=v0.w;
    vv[4]=v1.x; vv[5]=v1.y; vv[6]=v1.z; vv[7]=v1.w;
    vv[8]=v2.x; vv[9]=v2.y; vv[10]=v2.z; vv[11]=v2.w;
    vv[12]=v3.x; vv[13]=v3.y; vv[14]=v3.z; vv[15]=v3.w;
    float s = 0.f;
#pragma unroll
    for (int k = 0; k < Dd; k++) s = fmaf(vv[k], vv[k], s);
    g[p] = 0.5f * s - 0.125f;
    bf16x8 h0, h1;
#pragma unroll
    for (int k = 0; k < 8; k++) { h0[k] = (__bf16)vv[k]; h1[k] = (__bf16)vv[k + 8]; }
    bf16x8* dst = (bf16x8*)(xb + (size_t)p * Dd);
    dst[0] = h0; dst[1] = h1;
}

// ---------------- count + classify ----------------
// grid: 4 batches x 64 i-chunks = 256 blocks; block = 256 threads = 4 waves.
// Each wave owns 32 i-rows (one MFMA M-tile) and sweeps all 8192 j.
__device__ __forceinline__ void tile_step(const bf16x8 a, const bf16x8 bf,
                                          const float* gneg, const float gj,
                                          int* cnt) {
    f32x16 acc;
#pragma unroll
    for (int r = 0; r < 16; r++) acc[r] = gneg[r] - gj;   // -(g_i + g_j)
    acc = __builtin_amdgcn_mfma_f32_32x32x16_bf16(a, bf, acc, 0, 0, 0);
#pragma unroll
    for (int r = 0; r < 16; r++) cnt[r] += (acc[r] > 0.0f) ? 1 : 0;
}

__global__ __launch_bounds__(256)
void dbscan_count(const __bf16* __restrict__ xb, const float* __restrict__ g,
                  int* __restrict__ out) {
    const int b    = blockIdx.x >> 6;
    const int ic   = blockIdx.x & 63;
    const int w    = threadIdx.x >> 6;
    const int lane = threadIdx.x & 63;
    const int l31  = lane & 31;
    const int half = lane >> 5;

    const int i0 = ic * 128 + w * 32;
    const __bf16* xbb = xb + (size_t)b * Np * Dd;
    const float*  gb  = g + (size_t)b * Np;

    // A fragment: A[m = lane&31][k = 8*half + j], 8 contiguous bf16 = 16B load
    const bf16x8* afp = (const bf16x8*)xbb + (size_t)(i0 + l31) * 2 + half;
    const bf16x8 afrag = afp[0];

    // Per-lane row thresholds (negated): row r = (reg&3) + 8*(reg>>2) + 4*half
    float gneg[16];
    const float* gi = gb + i0 + 4 * half;
#pragma unroll
    for (int r = 0; r < 16; r++) gneg[r] = -gi[(r & 3) + 8 * (r >> 2)];

    // B fragment pointer (same per-lane shape as A); gcol pointer
    const bf16x8* bfp = (const bf16x8*)xbb + (size_t)l31 * 2 + half;
    const float*  gcp = gb + l31;

    int cnt[16];
#pragma unroll
    for (int r = 0; r < 16; r++) cnt[r] = 0;

    // 256 j-tiles of 32; unroll 2, prefetch depth 2 (wrap-around loads are safe)
    bf16x8 b0 = bfp[0], b1 = bfp[64];
    float  q0 = gcp[0], q1 = gcp[32];
#pragma unroll 1
    for (int jt = 0; jt < 256; jt += 2) {
        const int jn = (jt + 2) & 255;
        bf16x8 nb0 = bfp[(size_t)jn * 64];
        bf16x8 nb1 = bfp[(size_t)(jn + 1) * 64];
        float  nq0 = gcp[jn * 32];
        float  nq1 = gcp[jn * 32 + 32];
        tile_step(afrag, b0, gneg, q0, cnt);
        tile_step(afrag, b1, gneg, q1, cnt);
        b0 = nb0; b1 = nb1; q0 = nq0; q1 = nq1;
    }

    // Row totals: butterfly sum across the 32 lanes sharing each row
#pragma unroll
    for (int r = 0; r < 16; r++) {
        int v = cnt[r];
        v += __shfl_xor(v, 1);
        v += __shfl_xor(v, 2);
        v += __shfl_xor(v, 4);
        v += __shfl_xor(v, 8);
        v += __shfl_xor(v, 16);
        cnt[r] = v;
    }
    if (l31 == 0) {
        int* ob = out + (size_t)b * Np + i0 + 4 * half;
#pragma unroll
        for (int r = 0; r < 16; r++) {
            const int row = (r & 3) + 8 * (r >> 2);
            ob[row] = (cnt[r] < MIN_PTS) ? -1 : 0;
        }
    }
}

extern "C" void kernel_launch(void* const* d_in, const int* in_sizes, int n_in,
                              void* d_out, int out_size, void* d_ws, size_t ws_size,
                              hipStream_t stream) {
    const float* x = (const float*)d_in[0];
    int* out = (int*)d_out;

    __bf16* xb16 = (__bf16*)d_ws;                                  // 1 MB
    float*  gbuf = (float*)((char*)d_ws + (size_t)Bb * Np * Dd * 2); // 128 KB

    dbscan_prep<<<dim3(Bb * Np / 256), dim3(256), 0, stream>>>(x, xb16, gbuf);
    dbscan_count<<<dim3(256), dim3(256), 0, stream>>>(xb16, gbuf, out);
}

// Round 3
// 83.664 us; speedup vs baseline: 2.4182x; 1.9109x over previous
//
#include <hip/hip_runtime.h>

// DBSCAN neighbor-count + classify via augmented-K bf16 MFMA, MI355X (gfx950)
// B=4, N=8192, D=16 fp32 in, int32 out.
// dist(i,j) < 0.5  <=>  x_i.x_j - g_i - g_j > 0,  g_p = 0.5*||x_p||^2 - 0.125
// Augmented point (24 bf16 = 48 B): [x0..x15, 1.0, -g, 0,0,0,0,0,0]
//   A-frag row i uses k16..17 = [-g_i, 1] (swap), B-frag col j uses [1, -g_j]
//   => mfma_f32_16x16x32_bf16 with zero C emits S' = x_i.x_j - g_i - g_j directly.
// out[p] = (count_p < 10) ? -1 : 0

constexpr int Np = 8192;
constexpr int Bb = 4;
constexpr int MIN_PTS = 10;
constexpr int JS = 8;      // j-splits per i-chunk (occupancy: 4096 waves)
constexpr int RF = 4;      // A-fragments (16 rows each) per wave -> 64 rows

typedef __bf16 bf16x8 __attribute__((ext_vector_type(8)));
typedef float  f32x4  __attribute__((ext_vector_type(4)));

// ---------------- prep: fp32 -> augmented bf16; zero the count buffer -------
__global__ __launch_bounds__(256)
void dbscan_prep(const float* __restrict__ x, __bf16* __restrict__ aug,
                 int* __restrict__ out) {
    const int p = blockIdx.x * 256 + threadIdx.x;    // 32768 points
    const float4* src = (const float4*)(x + (size_t)p * 16);
    float4 v0 = src[0], v1 = src[1], v2 = src[2], v3 = src[3];
    float vv[16];
    vv[0]=v0.x; vv[1]=v0.y; vv[2]=v0.z; vv[3]=v0.w;
    vv[4]=v1.x; vv[5]=v1.y; vv[6]=v1.z; vv[7]=v1.w;
    vv[8]=v2.x; vv[9]=v2.y; vv[10]=v2.z; vv[11]=v2.w;
    vv[12]=v3.x; vv[13]=v3.y; vv[14]=v3.z; vv[15]=v3.w;
    float s = 0.f;
#pragma unroll
    for (int k = 0; k < 16; k++) s = fmaf(vv[k], vv[k], s);
    const float g = 0.5f * s - 0.125f;
    bf16x8 h0, h1, h2;
#pragma unroll
    for (int k = 0; k < 8; k++) { h0[k] = (__bf16)vv[k]; h1[k] = (__bf16)vv[k+8]; }
    h2[0] = (__bf16)1.0f; h2[1] = (__bf16)(-g);
#pragma unroll
    for (int k = 2; k < 8; k++) h2[k] = (__bf16)0.0f;
    bf16x8* dst = (bf16x8*)(aug + (size_t)p * 24);
    dst[0] = h0; dst[1] = h1; dst[2] = h2;
    out[p] = 0;
}

// ---------------- count: Gram sweep, atomicAdd partial counts ----------------
// 1024 blocks x 4 waves = 4096 waves. Wave W: i-chunk = W&511 (64 rows),
// j-split = W>>9 (1024 j). 4 blocks/CU -> 4 waves/SIMD.
__global__ __launch_bounds__(256, 4)
void dbscan_count(const __bf16* __restrict__ aug, int* __restrict__ out) {
    const int W    = blockIdx.x * 4 + (threadIdx.x >> 6);
    const int lane = threadIdx.x & 63;
    const int m    = lane & 15;          // A row / B col / C col within tile
    const int q    = lane >> 4;          // k-chunk (k = 8q..8q+7); C row group
    const int js   = W >> 9;
    const int chunk= W & 511;
    const int b    = chunk >> 7;
    const int ibase= (chunk & 127) * 64;
    const size_t pbase = (size_t)b * Np;

    // A fragments (loop-invariant). k16..23 lanes: [1,-g] -> [-g,1];
    // k24..31 lanes: zero (so B's overread garbage is multiplied by 0).
    bf16x8 af[RF];
#pragma unroll
    for (int f = 0; f < RF; f++) {
        const __bf16* ap = aug + (pbase + ibase + f*16 + m) * 24 + q * 8;
        bf16x8 a = *(const bf16x8*)ap;
        if (q == 2) { __bf16 t = a[0]; a[0] = a[1]; a[1] = t; }
        if (q == 3) {
#pragma unroll
            for (int k = 0; k < 8; k++) a[k] = (__bf16)0.0f;
        }
        af[f] = a;
    }

    const __bf16* bbase = aug + (pbase + (size_t)js * (Np / JS) + m) * 24 + q * 8;
    const f32x4 zacc = {0.f, 0.f, 0.f, 0.f};
    int cnt[16];
#pragma unroll
    for (int i = 0; i < 16; i++) cnt[i] = 0;

    // 64 j-tiles of 16 points; software prefetch depth 1 (wraps within window).
    bf16x8 bc = *(const bf16x8*)bbase;
#pragma unroll 2
    for (int t = 0; t < 64; t++) {
        const int tn = (t + 1) & 63;
        bf16x8 bn = *(const bf16x8*)(bbase + (size_t)tn * 16 * 24);
#pragma unroll
        for (int f = 0; f < RF; f++) {
            f32x4 acc = __builtin_amdgcn_mfma_f32_16x16x32_bf16(af[f], bc, zacc, 0, 0, 0);
            cnt[f*4+0] += (acc[0] > 0.0f) ? 1 : 0;
            cnt[f*4+1] += (acc[1] > 0.0f) ? 1 : 0;
            cnt[f*4+2] += (acc[2] > 0.0f) ? 1 : 0;
            cnt[f*4+3] += (acc[3] > 0.0f) ? 1 : 0;
        }
        bc = bn;
    }

    // Sum each (f,r) across the 16 lanes of the same q-group (cols 0..15).
#pragma unroll
    for (int i = 0; i < 16; i++) {
        int v = cnt[i];
        v += __shfl_xor(v, 1);
        v += __shfl_xor(v, 2);
        v += __shfl_xor(v, 4);
        v += __shfl_xor(v, 8);
        cnt[i] = v;
    }
    if (m == 0) {
        int* ob = out + pbase + ibase;
#pragma unroll
        for (int f = 0; f < RF; f++)
#pragma unroll
            for (int r = 0; r < 4; r++)
                atomicAdd(&ob[f*16 + q*4 + r], cnt[f*4+r]);
    }
}

// ---------------- classify ----------------
__global__ __launch_bounds__(256)
void dbscan_classify(int* __restrict__ out) {
    const int p = blockIdx.x * 256 + threadIdx.x;
    out[p] = (out[p] < MIN_PTS) ? -1 : 0;
}

extern "C" void kernel_launch(void* const* d_in, const int* in_sizes, int n_in,
                              void* d_out, int out_size, void* d_ws, size_t ws_size,
                              hipStream_t stream) {
    const float* x = (const float*)d_in[0];
    int* out = (int*)d_out;
    __bf16* aug = (__bf16*)d_ws;   // 32768 * 48 B = 1.5 MB (+64 B overread pad)

    dbscan_prep<<<dim3(Bb * Np / 256), dim3(256), 0, stream>>>(x, aug, out);
    dbscan_count<<<dim3(1024), dim3(256), 0, stream>>>(aug, out);
    dbscan_classify<<<dim3(Bb * Np / 256), dim3(256), 0, stream>>>(out);
}

// Round 4
// 82.954 us; speedup vs baseline: 2.4389x; 1.0086x over previous
//
#include <hip/hip_runtime.h>

// DBSCAN neighbor-count + classify via augmented-K bf16 MFMA, MI355X (gfx950)
// B=4, N=8192, D=16 fp32 in, int32 out.
// dist(i,j) < 0.5  <=>  x_i.x_j - g_i - g_j > 0,  g_p = 0.5*||x_p||^2 - 0.125
// Augmented point (24 bf16 = 48 B): [x0..x15, 1.0, -g, 0,0,0,0,0,0]
//   A-frag row i uses k16..17 = [-g_i, 1] (swap), B-frag col j uses [1, -g_j]
//   => mfma_f32_16x16x32_bf16 with zero C emits S' = x_i.x_j - g_i - g_j directly.
// out[p] = (count_p < 10) ? -1 : 0
//
// R4: JS 8->16 (2048 blocks, 8 waves/SIMD via __launch_bounds__(256,8));
//     per-wave B-window 24 KB -> L1-resident. Count kernel was latency-bound
//     at 4 waves/SIMD (R3).

constexpr int Np = 8192;
constexpr int Bb = 4;
constexpr int MIN_PTS = 10;
constexpr int JS = 16;     // j-splits per i-chunk -> 8192 waves total
constexpr int RF = 4;      // A-fragments (16 rows each) per wave -> 64 rows
constexpr int JW = Np / JS;        // 512 j per wave
constexpr int NT = JW / 16;        // 32 j-tiles per wave

typedef __bf16 bf16x8 __attribute__((ext_vector_type(8)));
typedef float  f32x4  __attribute__((ext_vector_type(4)));

// ---------------- prep: fp32 -> augmented bf16; zero the count buffer -------
__global__ __launch_bounds__(256)
void dbscan_prep(const float* __restrict__ x, __bf16* __restrict__ aug,
                 int* __restrict__ out) {
    const int p = blockIdx.x * 256 + threadIdx.x;    // 32768 points
    const float4* src = (const float4*)(x + (size_t)p * 16);
    float4 v0 = src[0], v1 = src[1], v2 = src[2], v3 = src[3];
    float vv[16];
    vv[0]=v0.x; vv[1]=v0.y; vv[2]=v0.z; vv[3]=v0.w;
    vv[4]=v1.x; vv[5]=v1.y; vv[6]=v1.z; vv[7]=v1.w;
    vv[8]=v2.x; vv[9]=v2.y; vv[10]=v2.z; vv[11]=v2.w;
    vv[12]=v3.x; vv[13]=v3.y; vv[14]=v3.z; vv[15]=v3.w;
    float s = 0.f;
#pragma unroll
    for (int k = 0; k < 16; k++) s = fmaf(vv[k], vv[k], s);
    const float g = 0.5f * s - 0.125f;
    bf16x8 h0, h1, h2;
#pragma unroll
    for (int k = 0; k < 8; k++) { h0[k] = (__bf16)vv[k]; h1[k] = (__bf16)vv[k+8]; }
    h2[0] = (__bf16)1.0f; h2[1] = (__bf16)(-g);
#pragma unroll
    for (int k = 2; k < 8; k++) h2[k] = (__bf16)0.0f;
    bf16x8* dst = (bf16x8*)(aug + (size_t)p * 24);
    dst[0] = h0; dst[1] = h1; dst[2] = h2;
    out[p] = 0;
}

// ---------------- count: Gram sweep, atomicAdd partial counts ----------------
// 2048 blocks x 4 waves = 8192 waves. Wave W: i-chunk = W&511 (64 rows),
// j-split = W>>9 (512 j). 8 blocks/CU -> 8 waves/SIMD; B-window 24 KB in L1.
__global__ __launch_bounds__(256, 8)
void dbscan_count(const __bf16* __restrict__ aug, int* __restrict__ out) {
    const int W    = blockIdx.x * 4 + (threadIdx.x >> 6);
    const int lane = threadIdx.x & 63;
    const int m    = lane & 15;          // A row / B col / C col within tile
    const int q    = lane >> 4;          // k-chunk (k = 8q..8q+7); C row group
    const int js   = W >> 9;             // [0,16)
    const int chunk= W & 511;
    const int b    = chunk >> 7;
    const int ibase= (chunk & 127) * 64;
    const size_t pbase = (size_t)b * Np;

    // A fragments (loop-invariant). k16..23 lanes: [1,-g] -> [-g,1];
    // k24..31 lanes: zero (so B's overread garbage is multiplied by 0).
    bf16x8 af[RF];
#pragma unroll
    for (int f = 0; f < RF; f++) {
        const __bf16* ap = aug + (pbase + ibase + f*16 + m) * 24 + q * 8;
        bf16x8 a = *(const bf16x8*)ap;
        if (q == 2) { __bf16 t = a[0]; a[0] = a[1]; a[1] = t; }
        if (q == 3) {
#pragma unroll
            for (int k = 0; k < 8; k++) a[k] = (__bf16)0.0f;
        }
        af[f] = a;
    }

    const __bf16* bbase = aug + (pbase + (size_t)js * JW + m) * 24 + q * 8;
    const f32x4 zacc = {0.f, 0.f, 0.f, 0.f};
    int cnt[16];
#pragma unroll
    for (int i = 0; i < 16; i++) cnt[i] = 0;

    // NT j-tiles of 16 points; software prefetch depth 1 (wraps within window).
    bf16x8 bc = *(const bf16x8*)bbase;
#pragma unroll 2
    for (int t = 0; t < NT; t++) {
        const int tn = (t + 1) & (NT - 1);
        bf16x8 bn = *(const bf16x8*)(bbase + (size_t)tn * 16 * 24);
#pragma unroll
        for (int f = 0; f < RF; f++) {
            f32x4 acc = __builtin_amdgcn_mfma_f32_16x16x32_bf16(af[f], bc, zacc, 0, 0, 0);
            cnt[f*4+0] += (acc[0] > 0.0f) ? 1 : 0;
            cnt[f*4+1] += (acc[1] > 0.0f) ? 1 : 0;
            cnt[f*4+2] += (acc[2] > 0.0f) ? 1 : 0;
            cnt[f*4+3] += (acc[3] > 0.0f) ? 1 : 0;
        }
        bc = bn;
    }

    // Sum each (f,r) across the 16 lanes of the same q-group (cols 0..15).
#pragma unroll
    for (int i = 0; i < 16; i++) {
        int v = cnt[i];
        v += __shfl_xor(v, 1);
        v += __shfl_xor(v, 2);
        v += __shfl_xor(v, 4);
        v += __shfl_xor(v, 8);
        cnt[i] = v;
    }
    if (m == 0) {
        int* ob = out + pbase + ibase;
#pragma unroll
        for (int f = 0; f < RF; f++)
#pragma unroll
            for (int r = 0; r < 4; r++)
                atomicAdd(&ob[f*16 + q*4 + r], cnt[f*4+r]);
    }
}

// ---------------- classify ----------------
__global__ __launch_bounds__(256)
void dbscan_classify(int* __restrict__ out) {
    const int p = blockIdx.x * 256 + threadIdx.x;
    out[p] = (out[p] < MIN_PTS) ? -1 : 0;
}

extern "C" void kernel_launch(void* const* d_in, const int* in_sizes, int n_in,
                              void* d_out, int out_size, void* d_ws, size_t ws_size,
                              hipStream_t stream) {
    const float* x = (const float*)d_in[0];
    int* out = (int*)d_out;
    __bf16* aug = (__bf16*)d_ws;   // 32768 * 48 B = 1.5 MB (+64 B overread pad)

    dbscan_prep<<<dim3(Bb * Np / 256), dim3(256), 0, stream>>>(x, aug, out);
    dbscan_count<<<dim3(Bb * (Np / 64) * JS / 4), dim3(256), 0, stream>>>(aug, out);
    dbscan_classify<<<dim3(Bb * Np / 256), dim3(256), 0, stream>>>(out);
}

// Round 5
// 80.736 us; speedup vs baseline: 2.5059x; 1.0275x over previous
//
#include <hip/hip_runtime.h>

// DBSCAN neighbor-count + classify via augmented-K bf16 MFMA, MI355X (gfx950)
// B=4, N=8192, D=16 fp32 in, int32 out.
// dist(i,j) < 0.5  <=>  x_i.x_j - g_i - g_j > 0,  g_p = 0.5*||x_p||^2 - 0.125
// Augmented point (24 bf16 = 48 B): [x0..x15, 1.0, -g, 0,0,0,0,0,0]
//   A-frag row i swaps k16..17 to [-g_i, 1]; B col j supplies [1, -g_j]
//   => mfma_f32_16x16x32_bf16 with zero C emits x_i.x_j - g_i - g_j directly.
//   A's k24..31 lanes are zeroed, so B's k24..31 content is irrelevant.
// out[p] = (count_p < 10) ? -1 : 0
//
// R5: B-window staged in LDS in fragment order. R3/R4 showed count stuck at
// ~32us independent of occupancy: co-resident blocks carry different js
// windows -> 192 KB L1 footprint -> every B load missed to L2. LDS staging
// removes the miss path from the inner loop entirely.

constexpr int Np = 8192;
constexpr int Bb = 4;
constexpr int MIN_PTS = 10;
constexpr int JS = 16;         // j-windows per batch
constexpr int JW = Np / JS;    // 512 j per window/block
constexpr int ICH = 256;       // i rows per block (4 waves x 64)
constexpr int RF = 4;          // A fragments per wave (16 rows each)
constexpr int NT = JW / 16;    // 32 j-tiles per window

typedef __bf16 bf16x8 __attribute__((ext_vector_type(8)));
typedef float  f32x4  __attribute__((ext_vector_type(4)));

// ---------------- prep: fp32 -> augmented bf16; zero the count buffer -------
__global__ __launch_bounds__(256)
void dbscan_prep(const float* __restrict__ x, __bf16* __restrict__ aug,
                 int* __restrict__ out) {
    const int p = blockIdx.x * 256 + threadIdx.x;    // 32768 points
    const float4* src = (const float4*)(x + (size_t)p * 16);
    float4 v0 = src[0], v1 = src[1], v2 = src[2], v3 = src[3];
    float vv[16];
    vv[0]=v0.x; vv[1]=v0.y; vv[2]=v0.z; vv[3]=v0.w;
    vv[4]=v1.x; vv[5]=v1.y; vv[6]=v1.z; vv[7]=v1.w;
    vv[8]=v2.x; vv[9]=v2.y; vv[10]=v2.z; vv[11]=v2.w;
    vv[12]=v3.x; vv[13]=v3.y; vv[14]=v3.z; vv[15]=v3.w;
    float s = 0.f;
#pragma unroll
    for (int k = 0; k < 16; k++) s = fmaf(vv[k], vv[k], s);
    const float g = 0.5f * s - 0.125f;
    bf16x8 h0, h1, h2;
#pragma unroll
    for (int k = 0; k < 8; k++) { h0[k] = (__bf16)vv[k]; h1[k] = (__bf16)vv[k+8]; }
    h2[0] = (__bf16)1.0f; h2[1] = (__bf16)(-g);
#pragma unroll
    for (int k = 2; k < 8; k++) h2[k] = (__bf16)0.0f;
    bf16x8* dst = (bf16x8*)(aug + (size_t)p * 24);
    dst[0] = h0; dst[1] = h1; dst[2] = h2;
    out[p] = 0;
}

// ---------------- count: LDS-staged Gram sweep, atomicAdd partials ----------
// grid: 4 b x 32 i-chunks x 16 j-windows = 2048 blocks, 256 threads.
// Block: stage 512-pt j-window (24 KB) into LDS in fragment order, then each
// of 4 waves runs 64 i-rows x 512 j. LDS caps residency at 6 blocks/CU.
__global__ __launch_bounds__(256, 6)
void dbscan_count(const __bf16* __restrict__ aug, int* __restrict__ out) {
    const int lane = threadIdx.x & 63;
    const int w    = threadIdx.x >> 6;
    const int m    = lane & 15;          // A/B row-col within tile
    const int q    = lane >> 4;          // k-chunk; C row group
    const int blk  = blockIdx.x;
    const int b    = blk >> 9;
    const int ic   = (blk >> 4) & 31;
    const int js   = blk & 15;
    const size_t pbase = (size_t)b * Np;
    const int ibase = ic * ICH;
    const int jbase = js * JW;

    // LDS: [tile][slot], slot = q*16+m for q<3, 8 bf16 per slot. 24.6 KB.
    __shared__ __bf16 ldsB[NT * 48 * 8];

    // Stage window: 1536 16B-chunks; chunk c = point p=c/3, piece r=c%3.
    {
        const __bf16* src = aug + (pbase + jbase) * 24;
#pragma unroll
        for (int it = 0; it < 6; it++) {
            const int c = threadIdx.x + it * 256;
            const int p = c / 3;
            const int r = c - p * 3;
            bf16x8 v = *(const bf16x8*)(src + (size_t)c * 8);
            *(bf16x8*)(ldsB + (((p >> 4) * 48) + r * 16 + (p & 15)) * 8) = v;
        }
    }

    // A fragments (global, loop-invariant; L2-hit). Rows: ibase+w*64+f*16+m.
    bf16x8 af[RF];
#pragma unroll
    for (int f = 0; f < RF; f++) {
        const __bf16* ap = aug + (pbase + ibase + w * 64 + f * 16 + m) * 24 + q * 8;
        bf16x8 a = *(const bf16x8*)ap;     // q=3 overreads into next point; zeroed below
        if (q == 2) { __bf16 t = a[0]; a[0] = a[1]; a[1] = t; }   // [1,-g] -> [-g,1]
        if (q == 3) {
#pragma unroll
            for (int k = 0; k < 8; k++) a[k] = (__bf16)0.0f;
        }
        af[f] = a;
    }

    __syncthreads();

    // B fragment address: q<3 -> slot q*16+m; q==3 -> broadcast slot 0 (dead input)
    const __bf16* bptr = ldsB + (q < 3 ? (q * 16 + m) * 8 : 0);

    const f32x4 zacc = {0.f, 0.f, 0.f, 0.f};
    int cnt[16];
#pragma unroll
    for (int i = 0; i < 16; i++) cnt[i] = 0;

    bf16x8 bc = *(const bf16x8*)bptr;
#pragma unroll 2
    for (int t = 0; t < NT; t++) {
        const int tn = (t + 1) & (NT - 1);
        bf16x8 bn = *(const bf16x8*)(bptr + tn * 48 * 8);   // depth-1 prefetch
#pragma unroll
        for (int f = 0; f < RF; f++) {
            f32x4 acc = __builtin_amdgcn_mfma_f32_16x16x32_bf16(af[f], bc, zacc, 0, 0, 0);
            cnt[f*4+0] += (acc[0] > 0.0f) ? 1 : 0;
            cnt[f*4+1] += (acc[1] > 0.0f) ? 1 : 0;
            cnt[f*4+2] += (acc[2] > 0.0f) ? 1 : 0;
            cnt[f*4+3] += (acc[3] > 0.0f) ? 1 : 0;
        }
        bc = bn;
    }

    // Sum across the 16 cols (lane bits 0..3), then 4 lanes (m==0) write rows.
#pragma unroll
    for (int i = 0; i < 16; i++) {
        int v = cnt[i];
        v += __shfl_xor(v, 1);
        v += __shfl_xor(v, 2);
        v += __shfl_xor(v, 4);
        v += __shfl_xor(v, 8);
        cnt[i] = v;
    }
    if (m == 0) {
        int* ob = out + pbase + ibase + w * 64;
#pragma unroll
        for (int f = 0; f < RF; f++)
#pragma unroll
            for (int r = 0; r < 4; r++)
                atomicAdd(&ob[f*16 + q*4 + r], cnt[f*4+r]);
    }
}

// ---------------- classify ----------------
__global__ __launch_bounds__(256)
void dbscan_classify(int* __restrict__ out) {
    const int p = blockIdx.x * 256 + threadIdx.x;
    out[p] = (out[p] < MIN_PTS) ? -1 : 0;
}

extern "C" void kernel_launch(void* const* d_in, const int* in_sizes, int n_in,
                              void* d_out, int out_size, void* d_ws, size_t ws_size,
                              hipStream_t stream) {
    const float* x = (const float*)d_in[0];
    int* out = (int*)d_out;
    __bf16* aug = (__bf16*)d_ws;   // 32768 * 48 B = 1.5 MB (+16 B overread pad)

    dbscan_prep<<<dim3(Bb * Np / 256), dim3(256), 0, stream>>>(x, aug, out);
    dbscan_count<<<dim3(Bb * 32 * JS), dim3(256), 0, stream>>>(aug, out);
    dbscan_classify<<<dim3(Bb * Np / 256), dim3(256), 0, stream>>>(out);
}